// Round 1
// baseline (3073.266 us; speedup 1.0000x reference)
//
#include <hip/hip_runtime.h>

#define D 64

// ---------------- degree / normalization ----------------

__global__ void deg_init_k(unsigned int* deg, int n) {
    int i = blockIdx.x * blockDim.x + threadIdx.x;
    if (i < n) deg[i] = 1u;  // self-loop
}

__global__ void deg_count_k(const int* __restrict__ col, unsigned int* deg, int E) {
    int e = blockIdx.x * blockDim.x + threadIdx.x;
    if (e < E) atomicAdd(&deg[col[e]], 1u);
}

__global__ void dinv_k(const unsigned int* __restrict__ deg, float* __restrict__ dinv, int n) {
    int i = blockIdx.x * blockDim.x + threadIdx.x;
    if (i < n) dinv[i] = rsqrtf((float)deg[i]);  // deg >= 1 always
}

// ---------------- propagation hop ----------------

// h_out[i] = dinv[i]^2 * h_in[i]   (the self-loop edge), also serves as init
__global__ void hop_init_k(const float* __restrict__ h_in, const float* __restrict__ dinv,
                           float* __restrict__ h_out, int n) {
    int t = blockIdx.x * blockDim.x + threadIdx.x;  // n*16 threads, float4 each
    int i = t >> 4;
    if (i >= n) return;
    int d4 = (t & 15) << 2;
    float w = dinv[i] * dinv[i];
    const float4 v = *(const float4*)(h_in + (size_t)i * D + d4);
    float4 r;
    r.x = w * v.x; r.y = w * v.y; r.z = w * v.z; r.w = w * v.w;
    *(float4*)(h_out + (size_t)i * D + d4) = r;
}

// h_out[i] += dinv[j]*dinv[i] * h_in[j] for every edge (j -> i)
__global__ void scatter_k(const int* __restrict__ row, const int* __restrict__ col,
                          const float* __restrict__ dinv, const float* __restrict__ h_in,
                          float* __restrict__ h_out, int E) {
    long long t = (long long)blockIdx.x * blockDim.x + threadIdx.x;  // E*16 threads
    int e = (int)(t >> 4);
    if (e >= E) return;
    int d4 = ((int)t & 15) << 2;
    int j = row[e];
    int i = col[e];
    float w = dinv[j] * dinv[i];
    const float4 v = *(const float4*)(h_in + (size_t)j * D + d4);
    float* dst = h_out + (size_t)i * D + d4;
    atomicAdd(dst + 0, w * v.x);
    atomicAdd(dst + 1, w * v.y);
    atomicAdd(dst + 2, w * v.z);
    atomicAdd(dst + 3, w * v.w);
}

// ---------------- linear + bias + relu ----------------

// out[i][o] = relu(sum_d h[i][d] * W[o][d] + b[o]); block = 256 thr = 4 nodes x 64 outs
__global__ __launch_bounds__(256) void linear_relu_k(const float* __restrict__ h,
                                                     const float* __restrict__ W,
                                                     const float* __restrict__ b,
                                                     float* __restrict__ out, int n) {
    __shared__ float Wt[D][D];   // Wt[d][o] = W[o][d]; lane index = o -> conflict-free
    __shared__ float bs[D];
    __shared__ float hrow[4][D]; // broadcast reads across a wave -> free
    int tid = threadIdx.x;
    for (int k = tid; k < D * D; k += 256) {
        Wt[k & 63][k >> 6] = W[k];  // W row-major [o][d]
    }
    if (tid < D) bs[tid] = b[tid];
    int li = tid >> 6;
    int o  = tid & 63;
    int i  = blockIdx.x * 4 + li;
    if (i < n) hrow[li][o] = h[(size_t)i * D + o];
    __syncthreads();
    if (i >= n) return;
    float acc = bs[o];
#pragma unroll
    for (int d = 0; d < D; ++d) acc = fmaf(hrow[li][d], Wt[d][o], acc);
    out[(size_t)i * D + o] = fmaxf(acc, 0.0f);
}

// ---------------- launch ----------------

extern "C" void kernel_launch(void* const* d_in, const int* in_sizes, int n_in,
                              void* d_out, int out_size, void* d_ws, size_t ws_size,
                              hipStream_t stream) {
    const float* x = (const float*)d_in[0];  // [n, 64]
    const float* W = (const float*)d_in[1];  // [64, 64]
    const float* b = (const float*)d_in[2];  // [64]
    const int*   ei = (const int*)d_in[3];   // [2, E] (int32 per harness convention)

    const int n = in_sizes[0] / D;
    const int E = in_sizes[3] / 2;
    const int* row = ei;       // sources j
    const int* col = ei + E;   // targets i

    float* out = (float*)d_out;

    // workspace layout (poisoned 0xAA each call -> everything initialized below)
    char* ws = (char*)d_ws;
    unsigned int* deg  = (unsigned int*)ws;                    // n u32
    float*        dinv = (float*)(ws + (size_t)n * 4);         // n f32
    float*        h1   = (float*)(ws + (size_t)n * 8);         // n*64 f32
    float*        h2   = h1 + (size_t)n * D;                   // n*64 f32

    deg_init_k<<<(n + 255) / 256, 256, 0, stream>>>(deg, n);
    deg_count_k<<<(E + 255) / 256, 256, 0, stream>>>(col, deg, E);
    dinv_k<<<(n + 255) / 256, 256, 0, stream>>>(deg, dinv, n);

    const int hop_blocks = (n * 16 + 255) / 256;
    const long long sc_threads = (long long)E * 16;
    const int sc_blocks = (int)((sc_threads + 255) / 256);

    // hop 1: x -> h1
    hop_init_k<<<hop_blocks, 256, 0, stream>>>(x, dinv, h1, n);
    scatter_k<<<sc_blocks, 256, 0, stream>>>(row, col, dinv, x, h1, E);
    // hop 2: h1 -> h2
    hop_init_k<<<hop_blocks, 256, 0, stream>>>(h1, dinv, h2, n);
    scatter_k<<<sc_blocks, 256, 0, stream>>>(row, col, dinv, h1, h2, E);

    // linear + bias + relu
    linear_relu_k<<<(n + 3) / 4, 256, 0, stream>>>(h2, W, b, out, n);
}

// Round 2
// 666.372 us; speedup vs baseline: 4.6119x; 4.6119x over previous
//
#include <hip/hip_runtime.h>

#define D 64

// ---------------- degree ----------------

__global__ void deg_init_k(unsigned int* deg, unsigned int* cursor, int n) {
    int i = blockIdx.x * blockDim.x + threadIdx.x;
    if (i < n) deg[i] = 1u;  // self-loop
    if (i == 0) *cursor = 0u;
}

__global__ void deg_count_k(const int* __restrict__ col, unsigned int* deg, int E) {
    int e = blockIdx.x * blockDim.x + threadIdx.x;
    if (e < E) atomicAdd(&deg[col[e]], 1u);
}

// ---------------- dinv + scan-free CSR segment allocation ----------------
// Per-wave prefix sum of edge counts; one global atomic per wave hands out a
// contiguous (unordered across nodes) segment. cur[i] = segment start; the
// bucket pass advances it to segment end; gather uses [cur-cnt, cur).

__global__ void alloc_k(const unsigned int* __restrict__ deg, float* __restrict__ dinv,
                        unsigned int* __restrict__ cur, unsigned int* cursor, int n) {
    int i = blockIdx.x * blockDim.x + threadIdx.x;
    int lane = threadIdx.x & 63;
    unsigned int dg = (i < n) ? deg[i] : 1u;
    if (i < n) dinv[i] = rsqrtf((float)dg);  // dg >= 1 always (self-loop)
    unsigned int cnt = (i < n) ? (dg - 1u) : 0u;  // in-edges only
    unsigned int v = cnt;  // inclusive wave scan
#pragma unroll
    for (int off = 1; off < 64; off <<= 1) {
        unsigned int t = (unsigned int)__shfl_up((int)v, off, 64);
        if (lane >= off) v += t;
    }
    unsigned int base = 0;
    if (lane == 63) base = atomicAdd(cursor, v);
    base = (unsigned int)__shfl((int)base, 63, 64);
    if (i < n) cur[i] = base + v - cnt;
}

// ---------------- bucket edges into CSR ----------------

__global__ void bucket_k(const int* __restrict__ row, const int* __restrict__ col,
                         const float* __restrict__ dinv, unsigned int* __restrict__ cur,
                         int* __restrict__ csr_src, float* __restrict__ csr_w, int E) {
    int e = blockIdx.x * blockDim.x + threadIdx.x;
    if (e >= E) return;
    int j = row[e], i = col[e];
    unsigned int pos = atomicAdd(&cur[i], 1u);
    csr_src[pos] = j;
    csr_w[pos] = dinv[j] * dinv[i];
}

// ---------------- hop 1: pure gather, one wave per node, lane = feature ----------------

__global__ __launch_bounds__(256) void gather_k(const float* __restrict__ h_in,
                                                const float* __restrict__ dinv,
                                                const unsigned int* __restrict__ deg,
                                                const unsigned int* __restrict__ cur,
                                                const int* __restrict__ csr_src,
                                                const float* __restrict__ csr_w,
                                                float* __restrict__ h_out, int n) {
    int w = threadIdx.x >> 6, lane = threadIdx.x & 63;
    int i = blockIdx.x * 4 + w;
    if (i >= n) return;
    float di = dinv[i];
    float acc = di * di * h_in[(size_t)i * D + lane];  // self-loop term
    unsigned int end = cur[i];
    unsigned int cnt = deg[i] - 1u;
    for (unsigned int e = end - cnt; e < end; ++e) {
        int j = csr_src[e];
        acc = fmaf(csr_w[e], h_in[(size_t)j * D + lane], acc);
    }
    h_out[(size_t)i * D + lane] = acc;
}

// ---------------- hop 2 fused with Linear + bias + ReLU ----------------

__global__ __launch_bounds__(256) void gather_linear_k(const float* __restrict__ h_in,
                                                       const float* __restrict__ dinv,
                                                       const unsigned int* __restrict__ deg,
                                                       const unsigned int* __restrict__ cur,
                                                       const int* __restrict__ csr_src,
                                                       const float* __restrict__ csr_w,
                                                       const float* __restrict__ W,
                                                       const float* __restrict__ b,
                                                       float* __restrict__ out, int n) {
    __shared__ float Wt[D][D];   // Wt[d][o] = W[o][d]; lane = o -> 2-way bank alias (free)
    __shared__ float sh[4][D];   // per-wave feature row
    int tid = threadIdx.x;
    for (int k = tid; k < D * D; k += 256) Wt[k & 63][k >> 6] = W[k];
    __syncthreads();
    int w = tid >> 6, lane = tid & 63;
    int i = blockIdx.x * 4 + w;
    if (i >= n) return;
    float di = dinv[i];
    float acc = di * di * h_in[(size_t)i * D + lane];
    unsigned int end = cur[i];
    unsigned int cnt = deg[i] - 1u;
    for (unsigned int e = end - cnt; e < end; ++e) {
        int j = csr_src[e];
        acc = fmaf(csr_w[e], h_in[(size_t)j * D + lane], acc);
    }
    sh[w][lane] = acc;  // same-wave write->read; compiler inserts lgkmcnt wait
    float o = b[lane];
#pragma unroll
    for (int d = 0; d < D; ++d) o = fmaf(sh[w][d], Wt[d][lane], o);
    out[(size_t)i * D + lane] = fmaxf(o, 0.0f);
}

// ---------------- launch ----------------

extern "C" void kernel_launch(void* const* d_in, const int* in_sizes, int n_in,
                              void* d_out, int out_size, void* d_ws, size_t ws_size,
                              hipStream_t stream) {
    const float* x = (const float*)d_in[0];  // [n, 64]
    const float* W = (const float*)d_in[1];  // [64, 64]
    const float* b = (const float*)d_in[2];  // [64]
    const int*   ei = (const int*)d_in[3];   // [2, E] int32

    const int n = in_sizes[0] / D;
    const int E = in_sizes[3] / 2;
    const int* row = ei;       // sources j
    const int* col = ei + E;   // targets i
    float* out = (float*)d_out;

    // ws layout (~39.6 MB): deg | dinv | cur | cursor(+pad) | csr_src | csr_w | h1
    char* ws = (char*)d_ws;
    unsigned int* deg     = (unsigned int*)ws;                           // n u32
    float*        dinv    = (float*)(ws + (size_t)n * 4);                // n f32
    unsigned int* cur     = (unsigned int*)(ws + (size_t)n * 8);         // n u32
    unsigned int* cursor  = (unsigned int*)(ws + (size_t)n * 12);        // 1 u32 (+12B pad)
    int*          csr_src = (int*)(ws + (size_t)n * 12 + 16);            // E i32
    float*        csr_w   = (float*)(ws + (size_t)n * 12 + 16 + (size_t)E * 4);  // E f32
    float*        h1      = (float*)(ws + (size_t)n * 12 + 16 + (size_t)E * 8);  // n*64 f32

    const int nb = (n + 255) / 256;
    const int eb = (E + 255) / 256;
    const int gb = (n + 3) / 4;

    deg_init_k<<<nb, 256, 0, stream>>>(deg, cursor, n);
    deg_count_k<<<eb, 256, 0, stream>>>(col, deg, E);
    alloc_k<<<nb, 256, 0, stream>>>(deg, dinv, cur, cursor, n);
    bucket_k<<<eb, 256, 0, stream>>>(row, col, dinv, cur, csr_src, csr_w, E);

    gather_k<<<gb, 256, 0, stream>>>(x, dinv, deg, cur, csr_src, csr_w, h1, n);
    gather_linear_k<<<gb, 256, 0, stream>>>(h1, dinv, deg, cur, csr_src, csr_w, W, b, out, n);
}